// Round 1
// baseline (2712.636 us; speedup 1.0000x reference)
//
#include <hip/hip_runtime.h>
#include <math.h>

// Sinkhorn loss, n=m=8192, K=32, eps=1, L=10 iterations.
// Never materializes C. Each pass recomputes d_ij = 2*x_i.y_j on the fly
// (K=32 fp32 dot), fused with bias+exp+row-logsumexp.
//
//   a_i = logmu - log sum_j exp(b_j + d_ij)      (f-pass: A=x, B=y)
//   b_j = lognu - log sum_i exp(a_i + d_ij)      (g-pass: A=y, B=x)
//   loss = sum_ij (xsq_i + ysq_j - d_ij) * exp(a_i + b_j + d_ij)
//
// No max-subtraction: exp args bounded well within fp32 range for this data.

#define KDIM 32
#define TILE_J 128
#define ROWS_WG 32

// ---------------------------------------------------------------- prep
__global__ void sink_prep(const float* __restrict__ x, const float* __restrict__ y,
                          int n, float* __restrict__ xsq, float* __restrict__ ysq,
                          float* __restrict__ bbuf) {
    int i = blockIdx.x * blockDim.x + threadIdx.x;
    if (i >= 2 * n) return;
    const float* src = (i < n) ? x : y;
    int r = (i < n) ? i : i - n;
    const float4* p = (const float4*)(src + (size_t)r * KDIM);
    float s = 0.f;
#pragma unroll
    for (int q = 0; q < 8; ++q) {
        float4 v = p[q];
        s += v.x * v.x + v.y * v.y + v.z * v.z + v.w * v.w;
    }
    if (i < n) xsq[r] = s;
    else { ysq[r] = s; bbuf[r] = -s; }  // b0 = g0 - ysq = -ysq
}

// ---------------------------------------------------------------- pass
// out[i] = logmarg - log( sum_j exp(bias[j] + 2*A_i.B_j) )
// A rows are staged scaled by 2 so the k-loop directly produces d = 2*A.B.
__global__ __launch_bounds__(256) void sink_pass(
    const float* __restrict__ A, const float* __restrict__ B,
    const float* __restrict__ bias, float* __restrict__ out,
    int n, float logmarg) {
    __shared__ float Al[KDIM][36];        // [k][row], stride 36 breaks conflicts
    __shared__ float Bl[KDIM][132];       // [k][col], stride 132
    __shared__ float biasl[TILE_J];
    __shared__ float red[ROWS_WG][33];

    const int tid = threadIdx.x;
    const int i0 = blockIdx.x * ROWS_WG;

    // stage A tile (32 rows x 32 k), scaled by 2, transposed to [k][r]
    {
        int r = tid >> 3, q = tid & 7;    // 256 threads -> 32 rows x 8 chunks
        float4 v = *(const float4*)(A + (size_t)(i0 + r) * KDIM + q * 4);
        Al[q * 4 + 0][r] = 2.f * v.x;
        Al[q * 4 + 1][r] = 2.f * v.y;
        Al[q * 4 + 2][r] = 2.f * v.z;
        Al[q * 4 + 3][r] = 2.f * v.w;
    }

    const int tr4 = (tid & 7) * 4;        // rows tr4..tr4+3
    const int tc4 = (tid >> 3) * 4;       // cols tc4..tc4+3 (of 128)
    float rs0 = 0.f, rs1 = 0.f, rs2 = 0.f, rs3 = 0.f;

    for (int j0 = 0; j0 < n; j0 += TILE_J) {
        __syncthreads();                  // protect Bl/biasl reuse (and Al on iter 0)
        // stage B tile (128 cols x 32 k) transposed; 4 float4 per thread
#pragma unroll
        for (int m = 0; m < 4; ++m) {
            int idx = tid + m * 256;      // 0..1023
            int c = idx >> 3, q = idx & 7;
            float4 v = *(const float4*)(B + (size_t)(j0 + c) * KDIM + q * 4);
            Bl[q * 4 + 0][c] = v.x;
            Bl[q * 4 + 1][c] = v.y;
            Bl[q * 4 + 2][c] = v.z;
            Bl[q * 4 + 3][c] = v.w;
        }
        if (tid < TILE_J) biasl[tid] = bias[j0 + tid];
        __syncthreads();

        float d[4][4] = {};
#pragma unroll
        for (int k = 0; k < KDIM; ++k) {
            const float4 av = *(const float4*)&Al[k][tr4];
            const float4 bv = *(const float4*)&Bl[k][tc4];
            d[0][0] = fmaf(av.x, bv.x, d[0][0]);
            d[0][1] = fmaf(av.x, bv.y, d[0][1]);
            d[0][2] = fmaf(av.x, bv.z, d[0][2]);
            d[0][3] = fmaf(av.x, bv.w, d[0][3]);
            d[1][0] = fmaf(av.y, bv.x, d[1][0]);
            d[1][1] = fmaf(av.y, bv.y, d[1][1]);
            d[1][2] = fmaf(av.y, bv.z, d[1][2]);
            d[1][3] = fmaf(av.y, bv.w, d[1][3]);
            d[2][0] = fmaf(av.z, bv.x, d[2][0]);
            d[2][1] = fmaf(av.z, bv.y, d[2][1]);
            d[2][2] = fmaf(av.z, bv.z, d[2][2]);
            d[2][3] = fmaf(av.z, bv.w, d[2][3]);
            d[3][0] = fmaf(av.w, bv.x, d[3][0]);
            d[3][1] = fmaf(av.w, bv.y, d[3][1]);
            d[3][2] = fmaf(av.w, bv.z, d[3][2]);
            d[3][3] = fmaf(av.w, bv.w, d[3][3]);
        }
#pragma unroll
        for (int ci = 0; ci < 4; ++ci) {
            const float bb = biasl[tc4 + ci];
            rs0 += __expf(bb + d[0][ci]);
            rs1 += __expf(bb + d[1][ci]);
            rs2 += __expf(bb + d[2][ci]);
            rs3 += __expf(bb + d[3][ci]);
        }
    }

    __syncthreads();
    const int tc = tid >> 3;
    red[tr4 + 0][tc] = rs0;
    red[tr4 + 1][tc] = rs1;
    red[tr4 + 2][tc] = rs2;
    red[tr4 + 3][tc] = rs3;
    __syncthreads();
    if (tid < ROWS_WG) {
        float s = 0.f;
#pragma unroll
        for (int c = 0; c < 32; ++c) s += red[tid][c];
        out[i0 + tid] = logmarg - __logf(s);
    }
}

// ---------------------------------------------------------------- loss
// partials[wg] = sum over this WG's 32 rows x all cols of C_ij * gamma_ij
__global__ __launch_bounds__(256) void sink_loss(
    const float* __restrict__ X, const float* __restrict__ Y,
    const float* __restrict__ abias, const float* __restrict__ bbias,
    const float* __restrict__ xsq, const float* __restrict__ ysq,
    float* __restrict__ partials, int n) {
    __shared__ float Al[KDIM][36];
    __shared__ float Bl[KDIM][132];
    __shared__ float bcl[TILE_J];
    __shared__ float ysl[TILE_J];
    __shared__ float red[256];

    const int tid = threadIdx.x;
    const int i0 = blockIdx.x * ROWS_WG;

    {
        int r = tid >> 3, q = tid & 7;
        float4 v = *(const float4*)(X + (size_t)(i0 + r) * KDIM + q * 4);
        Al[q * 4 + 0][r] = 2.f * v.x;
        Al[q * 4 + 1][r] = 2.f * v.y;
        Al[q * 4 + 2][r] = 2.f * v.z;
        Al[q * 4 + 3][r] = 2.f * v.w;
    }

    const int tr4 = (tid & 7) * 4;
    const int tc4 = (tid >> 3) * 4;
    // row-side scalars straight from global (L2-resident, read once)
    float ar[4], xs[4];
#pragma unroll
    for (int ri = 0; ri < 4; ++ri) {
        ar[ri] = abias[i0 + tr4 + ri];
        xs[ri] = xsq[i0 + tr4 + ri];
    }

    float acc = 0.f;
    for (int j0 = 0; j0 < n; j0 += TILE_J) {
        __syncthreads();
#pragma unroll
        for (int m = 0; m < 4; ++m) {
            int idx = tid + m * 256;
            int c = idx >> 3, q = idx & 7;
            float4 v = *(const float4*)(Y + (size_t)(j0 + c) * KDIM + q * 4);
            Bl[q * 4 + 0][c] = v.x;
            Bl[q * 4 + 1][c] = v.y;
            Bl[q * 4 + 2][c] = v.z;
            Bl[q * 4 + 3][c] = v.w;
        }
        if (tid < TILE_J) bcl[tid] = bbias[j0 + tid];
        else if (tid < 2 * TILE_J) ysl[tid - TILE_J] = ysq[j0 + tid - TILE_J];
        __syncthreads();

        float d[4][4] = {};
#pragma unroll
        for (int k = 0; k < KDIM; ++k) {
            const float4 av = *(const float4*)&Al[k][tr4];
            const float4 bv = *(const float4*)&Bl[k][tc4];
            d[0][0] = fmaf(av.x, bv.x, d[0][0]);
            d[0][1] = fmaf(av.x, bv.y, d[0][1]);
            d[0][2] = fmaf(av.x, bv.z, d[0][2]);
            d[0][3] = fmaf(av.x, bv.w, d[0][3]);
            d[1][0] = fmaf(av.y, bv.x, d[1][0]);
            d[1][1] = fmaf(av.y, bv.y, d[1][1]);
            d[1][2] = fmaf(av.y, bv.z, d[1][2]);
            d[1][3] = fmaf(av.y, bv.w, d[1][3]);
            d[2][0] = fmaf(av.z, bv.x, d[2][0]);
            d[2][1] = fmaf(av.z, bv.y, d[2][1]);
            d[2][2] = fmaf(av.z, bv.z, d[2][2]);
            d[2][3] = fmaf(av.z, bv.w, d[2][3]);
            d[3][0] = fmaf(av.w, bv.x, d[3][0]);
            d[3][1] = fmaf(av.w, bv.y, d[3][1]);
            d[3][2] = fmaf(av.w, bv.z, d[3][2]);
            d[3][3] = fmaf(av.w, bv.w, d[3][3]);
        }
#pragma unroll
        for (int ci = 0; ci < 4; ++ci) {
            const float bb = bcl[tc4 + ci];
            const float ys = ysl[tc4 + ci];
#pragma unroll
            for (int ri = 0; ri < 4; ++ri) {
                const float dd = d[ri][ci];
                const float w = __expf(ar[ri] + bb + dd);
                acc = fmaf(xs[ri] + ys - dd, w, acc);
            }
        }
    }

    __syncthreads();
    red[tid] = acc;
    __syncthreads();
#pragma unroll
    for (int s = 128; s > 0; s >>= 1) {
        if (tid < s) red[tid] += red[tid + s];
        __syncthreads();
    }
    if (tid == 0) partials[blockIdx.x] = red[0];
}

// ---------------------------------------------------------------- final reduce
__global__ void sink_reduce(const float* __restrict__ p, int nb,
                            float* __restrict__ out) {
    __shared__ float red[256];
    int tid = threadIdx.x;
    float v = 0.f;
    for (int i = tid; i < nb; i += 256) v += p[i];
    red[tid] = v;
    __syncthreads();
#pragma unroll
    for (int s = 128; s > 0; s >>= 1) {
        if (tid < s) red[tid] += red[tid + s];
        __syncthreads();
    }
    if (tid == 0) out[0] = red[0];
}

// ---------------------------------------------------------------- launch
extern "C" void kernel_launch(void* const* d_in, const int* in_sizes, int n_in,
                              void* d_out, int out_size, void* d_ws, size_t ws_size,
                              hipStream_t stream) {
    const float* x = (const float*)d_in[0];
    const float* y = (const float*)d_in[1];
    const int n = in_sizes[0] / KDIM;   // 8192
    const float logmarg = -logf((float)n);  // logmu == lognu (n == m)

    float* ws   = (float*)d_ws;
    float* xsq  = ws;
    float* ysq  = ws + n;
    float* abuf = ws + 2 * n;
    float* bbuf = ws + 3 * n;
    float* part = ws + 4 * n;

    const int nblk = n / ROWS_WG;       // 256

    sink_prep<<<(2 * n + 255) / 256, 256, 0, stream>>>(x, y, n, xsq, ysq, bbuf);
    for (int t = 0; t < 10; ++t) {
        sink_pass<<<nblk, 256, 0, stream>>>(x, y, bbuf, abuf, n, logmarg);  // f-pass
        sink_pass<<<nblk, 256, 0, stream>>>(y, x, abuf, bbuf, n, logmarg);  // g-pass
    }
    sink_loss<<<nblk, 256, 0, stream>>>(x, y, abuf, bbuf, xsq, ysq, part, n);
    sink_reduce<<<1, 256, 0, stream>>>(part, nblk, (float*)d_out);
}

// Round 2
// 1478.110 us; speedup vs baseline: 1.8352x; 1.8352x over previous
//
#include <hip/hip_runtime.h>
#include <math.h>

// Sinkhorn loss, n=m=8192, K=32, eps=1, L=10 iterations.
// Never materializes C. Each pass recomputes d_ij = 2*x_i.y_j on the fly
// (K=32 fp32 dot), fused with bias+exp+row partial-sums.
//
//   a_i = logmu - log sum_j exp(b_j + d_ij)      (f-pass: A=x, B=y)
//   b_j = lognu - log sum_i exp(a_i + d_ij)      (g-pass: A=y, B=x)
//   loss = sum_ij (xsq_i + ysq_j - d_ij) * exp(a_i + b_j + d_ij)
//
// Round 2: column dimension split into NS=4 slices -> grid (256 x 4) = 1024
// WGs (4 WG/CU, 16 waves/CU) to fix the 11% occupancy of round 1. Each pass
// writes per-slice partial exp-sums; the log-finalize is fused into the NEXT
// pass's bias staging (no extra kernels). Pass kernels pre-scale by log2(e)
// so the inner loop uses raw v_exp_f32.

#define KDIM 32
#define TILE_J 128
#define ROWS_WG 32
#define NS 4
#define LOG2E 1.44269504088896340736f

// ---------------------------------------------------------------- prep
__global__ void sink_prep(const float* __restrict__ x, const float* __restrict__ y,
                          int n, float* __restrict__ xsq, float* __restrict__ ysq,
                          float* __restrict__ nysq) {
    int i = blockIdx.x * blockDim.x + threadIdx.x;
    if (i >= 2 * n) return;
    const float* src = (i < n) ? x : y;
    int r = (i < n) ? i : i - n;
    const float4* p = (const float4*)(src + (size_t)r * KDIM);
    float s = 0.f;
#pragma unroll
    for (int q = 0; q < 8; ++q) {
        float4 v = p[q];
        s += v.x * v.x + v.y * v.y + v.z * v.z + v.w * v.w;
    }
    if (i < n) xsq[r] = s;
    else { ysq[r] = s; nysq[r] = -s; }  // b0 = g0 - ysq = -ysq
}

// ---------------------------------------------------------------- pass (partial)
// For rows [i0, i0+32) and cols [slice*n/NS, (slice+1)*n/NS):
//   psum_out[slice*n + i] = sum_j exp(bias_j + 2*A_i.B_j)
// bias_j = bias_direct[j] if given, else logmarg - log(sum_s psum_in[s*n+j]).
__global__ __launch_bounds__(256) void sink_pass_part(
    const float* __restrict__ A, const float* __restrict__ B,
    const float* __restrict__ bias_direct, const float* __restrict__ psum_in,
    float* __restrict__ psum_out, int n, float logmarg) {
    __shared__ float Al[KDIM][36];        // [k][row], scaled by 2*log2e
    __shared__ float Bl[KDIM][132];       // [k][col]
    __shared__ float biasl[TILE_J];       // scaled by log2e
    __shared__ float red[ROWS_WG][33];

    const int tid = threadIdx.x;
    const int i0 = blockIdx.x * ROWS_WG;
    const int jbeg = blockIdx.y * (n / NS);
    const int jend = jbeg + n / NS;

    {   // stage A tile (32 rows x 32 k), scaled, transposed to [k][r]
        int r = tid >> 3, q = tid & 7;
        float4 v = *(const float4*)(A + (size_t)(i0 + r) * KDIM + q * 4);
        const float sc = 2.f * LOG2E;
        Al[q * 4 + 0][r] = sc * v.x;
        Al[q * 4 + 1][r] = sc * v.y;
        Al[q * 4 + 2][r] = sc * v.z;
        Al[q * 4 + 3][r] = sc * v.w;
    }

    const int tr4 = (tid & 7) * 4;
    const int tc4 = (tid >> 3) * 4;
    float rs0 = 0.f, rs1 = 0.f, rs2 = 0.f, rs3 = 0.f;

    for (int j0 = jbeg; j0 < jend; j0 += TILE_J) {
        __syncthreads();
#pragma unroll
        for (int m = 0; m < 4; ++m) {
            int idx = tid + m * 256;
            int c = idx >> 3, q = idx & 7;
            float4 v = *(const float4*)(B + (size_t)(j0 + c) * KDIM + q * 4);
            Bl[q * 4 + 0][c] = v.x;
            Bl[q * 4 + 1][c] = v.y;
            Bl[q * 4 + 2][c] = v.z;
            Bl[q * 4 + 3][c] = v.w;
        }
        if (tid < TILE_J) {
            int j = j0 + tid;
            float b;
            if (bias_direct) {
                b = bias_direct[j];
            } else {
                float s = psum_in[j] + psum_in[n + j] + psum_in[2 * n + j] +
                          psum_in[3 * n + j];
                b = logmarg - __logf(s);
            }
            biasl[tid] = b * LOG2E;
        }
        __syncthreads();

        float d[4][4] = {};
#pragma unroll
        for (int k = 0; k < KDIM; ++k) {
            const float4 av = *(const float4*)&Al[k][tr4];
            const float4 bv = *(const float4*)&Bl[k][tc4];
            d[0][0] = fmaf(av.x, bv.x, d[0][0]);
            d[0][1] = fmaf(av.x, bv.y, d[0][1]);
            d[0][2] = fmaf(av.x, bv.z, d[0][2]);
            d[0][3] = fmaf(av.x, bv.w, d[0][3]);
            d[1][0] = fmaf(av.y, bv.x, d[1][0]);
            d[1][1] = fmaf(av.y, bv.y, d[1][1]);
            d[1][2] = fmaf(av.y, bv.z, d[1][2]);
            d[1][3] = fmaf(av.y, bv.w, d[1][3]);
            d[2][0] = fmaf(av.z, bv.x, d[2][0]);
            d[2][1] = fmaf(av.z, bv.y, d[2][1]);
            d[2][2] = fmaf(av.z, bv.z, d[2][2]);
            d[2][3] = fmaf(av.z, bv.w, d[2][3]);
            d[3][0] = fmaf(av.w, bv.x, d[3][0]);
            d[3][1] = fmaf(av.w, bv.y, d[3][1]);
            d[3][2] = fmaf(av.w, bv.z, d[3][2]);
            d[3][3] = fmaf(av.w, bv.w, d[3][3]);
        }
#pragma unroll
        for (int ci = 0; ci < 4; ++ci) {
            const float bb = biasl[tc4 + ci];
            rs0 += __builtin_amdgcn_exp2f(bb + d[0][ci]);
            rs1 += __builtin_amdgcn_exp2f(bb + d[1][ci]);
            rs2 += __builtin_amdgcn_exp2f(bb + d[2][ci]);
            rs3 += __builtin_amdgcn_exp2f(bb + d[3][ci]);
        }
    }

    __syncthreads();
    const int tc = tid >> 3;
    red[tr4 + 0][tc] = rs0;
    red[tr4 + 1][tc] = rs1;
    red[tr4 + 2][tc] = rs2;
    red[tr4 + 3][tc] = rs3;
    __syncthreads();
    if (tid < ROWS_WG) {
        float s = 0.f;
#pragma unroll
        for (int c = 0; c < 32; ++c) s += red[tid][c];
        psum_out[blockIdx.y * n + i0 + tid] = s;
    }
}

// ---------------------------------------------------------------- loss (partial)
// partials[wg] = sum over 32 rows x this slice's cols of C_ij * gamma_ij.
// abias/bbias finalized inline from apsum/bpsum.
__global__ __launch_bounds__(256) void sink_loss(
    const float* __restrict__ X, const float* __restrict__ Y,
    const float* __restrict__ apsum, const float* __restrict__ bpsum,
    const float* __restrict__ xsq, const float* __restrict__ ysq,
    float* __restrict__ partials, int n, float logmarg) {
    __shared__ float Al[KDIM][36];
    __shared__ float Bl[KDIM][132];
    __shared__ float bcl[TILE_J];
    __shared__ float ysl[TILE_J];
    __shared__ float arow[ROWS_WG];
    __shared__ float red[256];

    const int tid = threadIdx.x;
    const int i0 = blockIdx.x * ROWS_WG;
    const int jbeg = blockIdx.y * (n / NS);
    const int jend = jbeg + n / NS;

    {
        int r = tid >> 3, q = tid & 7;
        float4 v = *(const float4*)(X + (size_t)(i0 + r) * KDIM + q * 4);
        Al[q * 4 + 0][r] = 2.f * v.x;
        Al[q * 4 + 1][r] = 2.f * v.y;
        Al[q * 4 + 2][r] = 2.f * v.z;
        Al[q * 4 + 3][r] = 2.f * v.w;
    }
    if (tid < ROWS_WG) {
        int i = i0 + tid;
        float s = apsum[i] + apsum[n + i] + apsum[2 * n + i] + apsum[3 * n + i];
        arow[tid] = logmarg - __logf(s);
    }
    __syncthreads();

    const int tr4 = (tid & 7) * 4;
    const int tc4 = (tid >> 3) * 4;
    float ar[4], xs[4];
#pragma unroll
    for (int ri = 0; ri < 4; ++ri) {
        ar[ri] = arow[tr4 + ri];
        xs[ri] = xsq[i0 + tr4 + ri];
    }

    float acc = 0.f;
    for (int j0 = jbeg; j0 < jend; j0 += TILE_J) {
        __syncthreads();
#pragma unroll
        for (int m = 0; m < 4; ++m) {
            int idx = tid + m * 256;
            int c = idx >> 3, q = idx & 7;
            float4 v = *(const float4*)(Y + (size_t)(j0 + c) * KDIM + q * 4);
            Bl[q * 4 + 0][c] = v.x;
            Bl[q * 4 + 1][c] = v.y;
            Bl[q * 4 + 2][c] = v.z;
            Bl[q * 4 + 3][c] = v.w;
        }
        if (tid < TILE_J) {
            int j = j0 + tid;
            float s = bpsum[j] + bpsum[n + j] + bpsum[2 * n + j] + bpsum[3 * n + j];
            bcl[tid] = logmarg - __logf(s);
        } else if (tid < 2 * TILE_J) {
            ysl[tid - TILE_J] = ysq[j0 + tid - TILE_J];
        }
        __syncthreads();

        float d[4][4] = {};
#pragma unroll
        for (int k = 0; k < KDIM; ++k) {
            const float4 av = *(const float4*)&Al[k][tr4];
            const float4 bv = *(const float4*)&Bl[k][tc4];
            d[0][0] = fmaf(av.x, bv.x, d[0][0]);
            d[0][1] = fmaf(av.x, bv.y, d[0][1]);
            d[0][2] = fmaf(av.x, bv.z, d[0][2]);
            d[0][3] = fmaf(av.x, bv.w, d[0][3]);
            d[1][0] = fmaf(av.y, bv.x, d[1][0]);
            d[1][1] = fmaf(av.y, bv.y, d[1][1]);
            d[1][2] = fmaf(av.y, bv.z, d[1][2]);
            d[1][3] = fmaf(av.y, bv.w, d[1][3]);
            d[2][0] = fmaf(av.z, bv.x, d[2][0]);
            d[2][1] = fmaf(av.z, bv.y, d[2][1]);
            d[2][2] = fmaf(av.z, bv.z, d[2][2]);
            d[2][3] = fmaf(av.z, bv.w, d[2][3]);
            d[3][0] = fmaf(av.w, bv.x, d[3][0]);
            d[3][1] = fmaf(av.w, bv.y, d[3][1]);
            d[3][2] = fmaf(av.w, bv.z, d[3][2]);
            d[3][3] = fmaf(av.w, bv.w, d[3][3]);
        }
#pragma unroll
        for (int ci = 0; ci < 4; ++ci) {
            const float bb = bcl[tc4 + ci];
            const float ys = ysl[tc4 + ci];
#pragma unroll
            for (int ri = 0; ri < 4; ++ri) {
                const float dd = d[ri][ci];
                const float w = __expf(ar[ri] + bb + dd);
                acc = fmaf(xs[ri] + ys - dd, w, acc);
            }
        }
    }

    __syncthreads();
    red[tid] = acc;
    __syncthreads();
#pragma unroll
    for (int s = 128; s > 0; s >>= 1) {
        if (tid < s) red[tid] += red[tid + s];
        __syncthreads();
    }
    if (tid == 0) partials[blockIdx.y * gridDim.x + blockIdx.x] = red[0];
}

// ---------------------------------------------------------------- final reduce
__global__ void sink_reduce(const float* __restrict__ p, int nb,
                            float* __restrict__ out) {
    __shared__ float red[256];
    int tid = threadIdx.x;
    float v = 0.f;
    for (int i = tid; i < nb; i += 256) v += p[i];
    red[tid] = v;
    __syncthreads();
#pragma unroll
    for (int s = 128; s > 0; s >>= 1) {
        if (tid < s) red[tid] += red[tid + s];
        __syncthreads();
    }
    if (tid == 0) out[0] = red[0];
}

// ---------------------------------------------------------------- launch
extern "C" void kernel_launch(void* const* d_in, const int* in_sizes, int n_in,
                              void* d_out, int out_size, void* d_ws, size_t ws_size,
                              hipStream_t stream) {
    const float* x = (const float*)d_in[0];
    const float* y = (const float*)d_in[1];
    const int n = in_sizes[0] / KDIM;        // 8192
    const float logmarg = -logf((float)n);   // logmu == lognu (n == m)

    float* ws    = (float*)d_ws;
    float* xsq   = ws;                       // n
    float* ysq   = ws + n;                   // n
    float* nysq  = ws + 2 * n;               // n
    float* apsum = ws + 3 * n;               // NS*n
    float* bpsum = ws + (3 + NS) * n;        // NS*n
    float* part  = ws + (3 + 2 * NS) * n;    // nblk*NS

    const int nblk = n / ROWS_WG;            // 256
    dim3 grid(nblk, NS);

    sink_prep<<<(2 * n + 255) / 256, 256, 0, stream>>>(x, y, n, xsq, ysq, nysq);
    // f-pass 0: direct bias (-ysq) -> apsum
    sink_pass_part<<<grid, 256, 0, stream>>>(x, y, nysq, nullptr, apsum, n, logmarg);
    // g-pass 0: bias from apsum -> bpsum
    sink_pass_part<<<grid, 256, 0, stream>>>(y, x, nullptr, apsum, bpsum, n, logmarg);
    for (int t = 1; t < 10; ++t) {
        sink_pass_part<<<grid, 256, 0, stream>>>(x, y, nullptr, bpsum, apsum, n, logmarg);
        sink_pass_part<<<grid, 256, 0, stream>>>(y, x, nullptr, apsum, bpsum, n, logmarg);
    }
    sink_loss<<<grid, 256, 0, stream>>>(x, y, apsum, bpsum, xsq, ysq, part, n, logmarg);
    sink_reduce<<<1, 256, 0, stream>>>(part, nblk * NS, (float*)d_out);
}

// Round 3
// 534.725 us; speedup vs baseline: 5.0730x; 2.7642x over previous
//
#include <hip/hip_runtime.h>
#include <math.h>

// Sinkhorn loss, n=m=8192, K=32, eps=1, L=10 iterations.
// Round 3: bf16-split MFMA formulation.
//   d_ij = x_i . y_j  computed as  xh.yh + xh.yl + xl.yh  (bf16 hi/lo split,
//   ~2^-16 relative accuracy) on the matrix pipe via mfma_f32_16x16x32_bf16.
//   exp arg uses exp2: exp(b + 2d) = exp2(b_l2e + (2*log2e)*d).
// Per-pass partial exp-sums over NS column slices; a tiny finalize kernel
// turns psums into the next pass's l2e-scaled bias (removes the x64
// redundant logsumexp of round 2). Main loops have NO LDS and NO barriers:
// fragments come straight from L2 (inputs ~2 MB, fully resident).
//
// MFMA layouts (m89/m120-verified on gfx950):
//   A: elem j of frag = A[m=lane&15][k=(lane>>4)*8+j]
//   B: elem j of frag = B[k=(lane>>4)*8+j][n=lane&15]   (= Y[lane&15][k])
//   C/D: col=lane&15, row=(lane>>4)*4+reg

#define KDIM 32
#define NS 16
#define LOG2E 1.44269504088896340736f

typedef short short8 __attribute__((ext_vector_type(8)));
typedef float f32x4 __attribute__((ext_vector_type(4)));

__device__ __forceinline__ unsigned short f2bf(float f) {
    unsigned int u = __float_as_uint(f);
    u += 0x7FFF + ((u >> 16) & 1);          // round-to-nearest-even
    return (unsigned short)(u >> 16);
}
__device__ __forceinline__ float bf2f(unsigned short b) {
    return __uint_as_float(((unsigned int)b) << 16);
}

// ------------------------------------------------------------ prep: hi/lo split
__global__ void prep_split(const float* __restrict__ x, const float* __restrict__ y,
                           int nelem,
                           unsigned short* __restrict__ xh, unsigned short* __restrict__ xl,
                           unsigned short* __restrict__ yh, unsigned short* __restrict__ yl) {
    int i4 = (blockIdx.x * 256 + threadIdx.x) * 4;
    if (i4 >= 2 * nelem) return;
    const float* src; unsigned short* dh; unsigned short* dl; int off;
    if (i4 < nelem) { src = x; dh = xh; dl = xl; off = i4; }
    else            { src = y; dh = yh; dl = yl; off = i4 - nelem; }
    float4 v = *(const float4*)(src + off);
    ushort4 h, l;
    h.x = f2bf(v.x); l.x = f2bf(v.x - bf2f(h.x));
    h.y = f2bf(v.y); l.y = f2bf(v.y - bf2f(h.y));
    h.z = f2bf(v.z); l.z = f2bf(v.z - bf2f(h.z));
    h.w = f2bf(v.w); l.w = f2bf(v.w - bf2f(h.w));
    *(ushort4*)(dh + off) = h;
    *(ushort4*)(dl + off) = l;
}

// ------------------------------------------------------------ prep: row sumsq
// xsq[i], ysq[j]; b_l2e init = l2e * (-ysq_j)  (g0 = 0)
__global__ void prep_sq(const float* __restrict__ x, const float* __restrict__ y,
                        int n, float* __restrict__ xsq, float* __restrict__ ysq,
                        float* __restrict__ b_l2e) {
    int i = blockIdx.x * blockDim.x + threadIdx.x;
    if (i >= 2 * n) return;
    const float* src = (i < n) ? x : y;
    int r = (i < n) ? i : i - n;
    const float4* p = (const float4*)(src + (size_t)r * KDIM);
    float s = 0.f;
#pragma unroll
    for (int q = 0; q < 8; ++q) {
        float4 v = p[q];
        s += v.x * v.x + v.y * v.y + v.z * v.z + v.w * v.w;
    }
    if (i < n) xsq[r] = s;
    else { ysq[r] = s; b_l2e[r] = -LOG2E * s; }
}

// ------------------------------------------------------------ pass
// psum_out[slice*n + i] = sum_{j in slice} exp(bias_j + 2*A_i.B_j)
// bias_l2e holds l2e-scaled bias. Wave = one 32-row block; WG = 4 waves.
__global__ __launch_bounds__(256) void sink_pass(
    const unsigned short* __restrict__ Ah, const unsigned short* __restrict__ Alo,
    const unsigned short* __restrict__ Bh, const unsigned short* __restrict__ Blo,
    const float* __restrict__ bias_l2e, float* __restrict__ psum_out, int n) {
    const int tid = threadIdx.x;
    const int w = tid >> 6, lane = tid & 63;
    const int mrow = lane & 15, koff = (lane >> 4) * 8;
    const int i0 = (blockIdx.x * 4 + w) * 32;
    const int jbeg = blockIdx.y * (n / NS);

    short8 aH[2], aL[2];
#pragma unroll
    for (int t = 0; t < 2; ++t) {
        size_t rb = (size_t)(i0 + t * 16 + mrow) * KDIM + koff;
        aH[t] = *(const short8*)(Ah + rb);
        aL[t] = *(const short8*)(Alo + rb);
    }

    float rs[8] = {0.f, 0.f, 0.f, 0.f, 0.f, 0.f, 0.f, 0.f};
    const float c2 = 2.0f * LOG2E;

    for (int jt = 0; jt < n / NS; jt += 32) {
        const int j0 = jbeg + jt;
        short8 bH[2], bL[2]; float bc[2];
#pragma unroll
        for (int u = 0; u < 2; ++u) {
            size_t rb = (size_t)(j0 + u * 16 + mrow) * KDIM + koff;
            bH[u] = *(const short8*)(Bh + rb);
            bL[u] = *(const short8*)(Blo + rb);
            bc[u] = bias_l2e[j0 + u * 16 + mrow];
        }
        f32x4 d[2][2];
#pragma unroll
        for (int t = 0; t < 2; ++t)
#pragma unroll
            for (int u = 0; u < 2; ++u) {
                f32x4 acc = {0.f, 0.f, 0.f, 0.f};
                acc = __builtin_amdgcn_mfma_f32_16x16x32_bf16(aH[t], bH[u], acc, 0, 0, 0);
                acc = __builtin_amdgcn_mfma_f32_16x16x32_bf16(aH[t], bL[u], acc, 0, 0, 0);
                acc = __builtin_amdgcn_mfma_f32_16x16x32_bf16(aL[t], bH[u], acc, 0, 0, 0);
                d[t][u] = acc;
            }
#pragma unroll
        for (int t = 0; t < 2; ++t)
#pragma unroll
            for (int u = 0; u < 2; ++u)
#pragma unroll
                for (int r = 0; r < 4; ++r)
                    rs[t * 4 + r] += __builtin_amdgcn_exp2f(fmaf(d[t][u][r], c2, bc[u]));
    }

    // cross-lane row reduction: row = t*16 + (lane>>4)*4 + r, col-slot = mrow
    __shared__ float red[4][32][17];
#pragma unroll
    for (int t = 0; t < 2; ++t)
#pragma unroll
        for (int r = 0; r < 4; ++r)
            red[w][t * 16 + ((lane >> 4) << 2) + r][mrow] = rs[t * 4 + r];
    __syncthreads();
    if (tid < 128) {
        int w2 = tid >> 5, row = tid & 31;
        float s = 0.f;
#pragma unroll
        for (int c = 0; c < 16; ++c) s += red[w2][row][c];
        psum_out[(size_t)blockIdx.y * n + (blockIdx.x * 4 + w2) * 32 + row] = s;
    }
}

// ------------------------------------------------------------ finalize
// out_l2e[j] = l2e*logmarg - log2( sum_s psum[s*n+j] )
__global__ void sink_finalize(const float* __restrict__ psum,
                              float* __restrict__ out_l2e, int n, float base_l2e) {
    int j = blockIdx.x * 256 + threadIdx.x;
    if (j >= n) return;
    float s = 0.f;
#pragma unroll
    for (int k = 0; k < NS; ++k) s += psum[(size_t)k * n + j];
    out_l2e[j] = base_l2e - __log2f(s);
}

// ------------------------------------------------------------ loss
// partials = sum_ij (xsq_i + ysq_j - 2d) * exp(a + b + 2d), d = x_i.y_j
__global__ __launch_bounds__(256) void sink_loss(
    const unsigned short* __restrict__ Xh, const unsigned short* __restrict__ Xl,
    const unsigned short* __restrict__ Yh, const unsigned short* __restrict__ Yl,
    const float* __restrict__ a_l2e, const float* __restrict__ b_l2e,
    const float* __restrict__ xsq, const float* __restrict__ ysq,
    float* __restrict__ partials, int n) {
    const int tid = threadIdx.x;
    const int w = tid >> 6, lane = tid & 63;
    const int mrow = lane & 15, koff = (lane >> 4) * 8;
    const int i0 = (blockIdx.x * 4 + w) * 32;
    const int jbeg = blockIdx.y * (n / NS);

    short8 aH[2], aL[2];
    float ar[8], xs[8];
#pragma unroll
    for (int t = 0; t < 2; ++t) {
        size_t rb = (size_t)(i0 + t * 16 + mrow) * KDIM + koff;
        aH[t] = *(const short8*)(Xh + rb);
        aL[t] = *(const short8*)(Xl + rb);
#pragma unroll
        for (int r = 0; r < 4; ++r) {
            int g = i0 + t * 16 + ((lane >> 4) << 2) + r;
            ar[t * 4 + r] = a_l2e[g];
            xs[t * 4 + r] = xsq[g];
        }
    }

    const float c2 = 2.0f * LOG2E;
    float acc = 0.f;

    for (int jt = 0; jt < n / NS; jt += 32) {
        const int j0 = jbeg + jt;
        short8 bH[2], bL[2]; float bc[2], ysv[2];
#pragma unroll
        for (int u = 0; u < 2; ++u) {
            size_t rb = (size_t)(j0 + u * 16 + mrow) * KDIM + koff;
            bH[u] = *(const short8*)(Yh + rb);
            bL[u] = *(const short8*)(Yl + rb);
            bc[u] = b_l2e[j0 + u * 16 + mrow];
            ysv[u] = ysq[j0 + u * 16 + mrow];
        }
        f32x4 d[2][2];
#pragma unroll
        for (int t = 0; t < 2; ++t)
#pragma unroll
            for (int u = 0; u < 2; ++u) {
                f32x4 z = {0.f, 0.f, 0.f, 0.f};
                z = __builtin_amdgcn_mfma_f32_16x16x32_bf16(aH[t], bH[u], z, 0, 0, 0);
                z = __builtin_amdgcn_mfma_f32_16x16x32_bf16(aH[t], bL[u], z, 0, 0, 0);
                z = __builtin_amdgcn_mfma_f32_16x16x32_bf16(aL[t], bH[u], z, 0, 0, 0);
                d[t][u] = z;
            }
#pragma unroll
        for (int t = 0; t < 2; ++t)
#pragma unroll
            for (int u = 0; u < 2; ++u)
#pragma unroll
                for (int r = 0; r < 4; ++r) {
                    float dd = d[t][u][r];
                    float wgt = __builtin_amdgcn_exp2f(fmaf(dd, c2, ar[t * 4 + r] + bc[u]));
                    float cst = fmaf(dd, -2.f, xs[t * 4 + r] + ysv[u]);
                    acc = fmaf(cst, wgt, acc);
                }
    }

    __shared__ float red[256];
    red[tid] = acc;
    __syncthreads();
#pragma unroll
    for (int s = 128; s > 0; s >>= 1) {
        if (tid < s) red[tid] += red[tid + s];
        __syncthreads();
    }
    if (tid == 0) partials[blockIdx.y * gridDim.x + blockIdx.x] = red[0];
}

// ------------------------------------------------------------ final reduce
__global__ void sink_reduce(const float* __restrict__ p, int nb,
                            float* __restrict__ out) {
    __shared__ float red[256];
    int tid = threadIdx.x;
    float v = 0.f;
    for (int i = tid; i < nb; i += 256) v += p[i];
    red[tid] = v;
    __syncthreads();
#pragma unroll
    for (int s = 128; s > 0; s >>= 1) {
        if (tid < s) red[tid] += red[tid + s];
        __syncthreads();
    }
    if (tid == 0) out[0] = red[0];
}

// ------------------------------------------------------------ launch
extern "C" void kernel_launch(void* const* d_in, const int* in_sizes, int n_in,
                              void* d_out, int out_size, void* d_ws, size_t ws_size,
                              hipStream_t stream) {
    const float* x = (const float*)d_in[0];
    const float* y = (const float*)d_in[1];
    const int n = in_sizes[0] / KDIM;                 // 8192
    const int nelem = n * KDIM;
    const float base_l2e = -LOG2E * logf((float)n);   // l2e * logmarg

    float* ws = (float*)d_ws;
    float* xsq   = ws;                                //  n
    float* ysq   = ws + n;                            //  n
    float* a_l2e = ws + 2 * n;                        //  n
    float* b_l2e = ws + 3 * n;                        //  n
    float* apsum = ws + 4 * n;                        //  NS*n
    float* bpsum = ws + (4 + NS) * n;                 //  NS*n
    float* part  = ws + (4 + 2 * NS) * n;             //  64*NS (pad to n)
    unsigned short* us = (unsigned short*)(ws + (5 + 2 * NS) * n);
    unsigned short* xh = us;                          //  nelem
    unsigned short* xl = us + nelem;
    unsigned short* yh = us + 2 * nelem;
    unsigned short* yl = us + 3 * nelem;

    const int rowwg = n / 128;                        // 64 (4 waves x 32 rows)
    dim3 grid(rowwg, NS);

    prep_split<<<(2 * nelem / 4 + 255) / 256, 256, 0, stream>>>(x, y, nelem, xh, xl, yh, yl);
    prep_sq<<<(2 * n + 255) / 256, 256, 0, stream>>>(x, y, n, xsq, ysq, b_l2e);

    for (int t = 0; t < 10; ++t) {
        sink_pass<<<grid, 256, 0, stream>>>(xh, xl, yh, yl, b_l2e, apsum, n);
        sink_finalize<<<(n + 255) / 256, 256, 0, stream>>>(apsum, a_l2e, n, base_l2e);
        sink_pass<<<grid, 256, 0, stream>>>(yh, yl, xh, xl, a_l2e, bpsum, n);
        sink_finalize<<<(n + 255) / 256, 256, 0, stream>>>(bpsum, b_l2e, n, base_l2e);
    }
    sink_loss<<<grid, 256, 0, stream>>>(xh, xl, yh, yl, a_l2e, b_l2e, xsq, ysq, part, n);
    sink_reduce<<<1, 256, 0, stream>>>(part, rowwg * NS, (float*)d_out);
}

// Round 4
// 447.940 us; speedup vs baseline: 6.0558x; 1.1937x over previous
//
#include <hip/hip_runtime.h>
#include <math.h>

// Sinkhorn loss, n=m=8192, K=32, eps=1, L=10 iterations.
// Round 4: bf16-split MFMA + 64 rows/wave (halves B-fragment VMEM traffic)
// + per-pass inline bias finalize (no separate finalize kernels; 24 dispatches).
//   d_ij = x_i.y_j via xh.yh + xh.yl + xl.yh (bf16 hi/lo split) on MFMA pipe.
//   pass:  psum_out[slice*n+i] = sum_{j in slice} exp2(biasl2e_j + 2*l2e*d_ij)
//          biasl2e finalized in-prologue from the 32-slice psums of prev pass.
//   loss:  sum_ij (xsq_i + ysq_j - 2d) * exp2(a_l2e + b_l2e + 2*l2e*d)
// MFMA layouts (m89/m120-verified): A elem j = A[m=lane&15][k=(lane>>4)*8+j];
// C/D: col=lane&15, row=(lane>>4)*4+reg.

#define KDIM 32
#define NPS 32                    // psum slices (pass grid.y)
#define NSL_LOSS 16               // loss grid.y
#define LOG2E 1.44269504088896340736f

typedef short short8 __attribute__((ext_vector_type(8)));
typedef float f32x4 __attribute__((ext_vector_type(4)));

__device__ __forceinline__ unsigned short f2bf(float f) {
    unsigned int u = __float_as_uint(f);
    u += 0x7FFF + ((u >> 16) & 1);
    return (unsigned short)(u >> 16);
}
__device__ __forceinline__ float bf2f(unsigned short b) {
    return __uint_as_float(((unsigned int)b) << 16);
}

// ------------------------------------------------------------ prep: hi/lo split
__global__ void prep_split(const float* __restrict__ x, const float* __restrict__ y,
                           int nelem,
                           unsigned short* __restrict__ xh, unsigned short* __restrict__ xl,
                           unsigned short* __restrict__ yh, unsigned short* __restrict__ yl) {
    int i4 = (blockIdx.x * 256 + threadIdx.x) * 4;
    if (i4 >= 2 * nelem) return;
    const float* src; unsigned short* dh; unsigned short* dl; int off;
    if (i4 < nelem) { src = x; dh = xh; dl = xl; off = i4; }
    else            { src = y; dh = yh; dl = yl; off = i4 - nelem; }
    float4 v = *(const float4*)(src + off);
    ushort4 h, l;
    h.x = f2bf(v.x); l.x = f2bf(v.x - bf2f(h.x));
    h.y = f2bf(v.y); l.y = f2bf(v.y - bf2f(h.y));
    h.z = f2bf(v.z); l.z = f2bf(v.z - bf2f(h.z));
    h.w = f2bf(v.w); l.w = f2bf(v.w - bf2f(h.w));
    *(ushort4*)(dh + off) = h;
    *(ushort4*)(dl + off) = l;
}

// ------------------------------------------------------------ prep: row sumsq
__global__ void prep_sq(const float* __restrict__ x, const float* __restrict__ y,
                        int n, float* __restrict__ xsq, float* __restrict__ ysq,
                        float* __restrict__ b_l2e) {
    int i = blockIdx.x * blockDim.x + threadIdx.x;
    if (i >= 2 * n) return;
    const float* src = (i < n) ? x : y;
    int r = (i < n) ? i : i - n;
    const float4* p = (const float4*)(src + (size_t)r * KDIM);
    float s = 0.f;
#pragma unroll
    for (int q = 0; q < 8; ++q) {
        float4 v = p[q];
        s += v.x * v.x + v.y * v.y + v.z * v.z + v.w * v.w;
    }
    if (i < n) xsq[r] = s;
    else { ysq[r] = s; b_l2e[r] = -LOG2E * s; }   // b0 = g0 - ysq
}

// ------------------------------------------------------------ pass
// Wave = 64 rows; WG = 4 waves = 256 rows. grid = (n/256, NPS).
// Slice = n/NPS = 256 cols. Prologue finalizes l2e-bias for the slice.
__global__ __launch_bounds__(256, 4) void sink_pass(
    const unsigned short* __restrict__ Ah, const unsigned short* __restrict__ Alo,
    const unsigned short* __restrict__ Bh, const unsigned short* __restrict__ Blo,
    const float* __restrict__ bias_direct,   // pass 0: l2e-scaled bias, else null
    const float* __restrict__ psum_in,       // NPS-slice psums of prev pass
    float* __restrict__ psum_out, int n, float base_l2e) {
    __shared__ float biasl[256];
    __shared__ float red[4][64][17];

    const int tid = threadIdx.x;
    const int w = tid >> 6, lane = tid & 63;
    const int mrow = lane & 15, quad = lane >> 4, koff = quad * 8;
    const int i0 = (blockIdx.x * 4 + w) * 64;
    const int jbeg = blockIdx.y * (n / NPS);

    {   // prologue: bias for this slice's 256 cols (1 col/thread)
        int c = jbeg + tid;
        float b;
        if (bias_direct) {
            b = bias_direct[c];
        } else {
            float s = 0.f;
#pragma unroll
            for (int k = 0; k < NPS; ++k) s += psum_in[(size_t)k * n + c];
            b = base_l2e - __log2f(s);
        }
        biasl[tid] = b;
    }

    short8 aH[4], aL[4];
#pragma unroll
    for (int t = 0; t < 4; ++t) {
        size_t rb = (size_t)(i0 + t * 16 + mrow) * KDIM + koff;
        aH[t] = *(const short8*)(Ah + rb);
        aL[t] = *(const short8*)(Alo + rb);
    }
    __syncthreads();

    float rs[16];
#pragma unroll
    for (int q = 0; q < 16; ++q) rs[q] = 0.f;
    const float c2 = 2.0f * LOG2E;

    for (int jt = 0; jt < n / NPS; jt += 32) {
        const int j0 = jbeg + jt;
        short8 bH[2], bL[2]; float bc[2];
#pragma unroll
        for (int u = 0; u < 2; ++u) {
            size_t rb = (size_t)(j0 + u * 16 + mrow) * KDIM + koff;
            bH[u] = *(const short8*)(Bh + rb);
            bL[u] = *(const short8*)(Blo + rb);
            bc[u] = biasl[jt + u * 16 + mrow];
        }
#pragma unroll
        for (int t = 0; t < 4; ++t)
#pragma unroll
            for (int u = 0; u < 2; ++u) {
                f32x4 z = {0.f, 0.f, 0.f, 0.f};
                z = __builtin_amdgcn_mfma_f32_16x16x32_bf16(aH[t], bH[u], z, 0, 0, 0);
                z = __builtin_amdgcn_mfma_f32_16x16x32_bf16(aH[t], bL[u], z, 0, 0, 0);
                z = __builtin_amdgcn_mfma_f32_16x16x32_bf16(aL[t], bH[u], z, 0, 0, 0);
#pragma unroll
                for (int r = 0; r < 4; ++r)
                    rs[t * 4 + r] += __builtin_amdgcn_exp2f(fmaf(z[r], c2, bc[u]));
            }
    }

    // cross-lane row reduction: row = t*16 + quad*4 + r held by 16 mrow-lanes
#pragma unroll
    for (int t = 0; t < 4; ++t)
#pragma unroll
        for (int r = 0; r < 4; ++r)
            red[w][t * 16 + quad * 4 + r][mrow] = rs[t * 4 + r];
    __syncthreads();
    {
        int w2 = tid >> 6, row = tid & 63;
        float s = 0.f;
#pragma unroll
        for (int c = 0; c < 16; ++c) s += red[w2][row][c];
        psum_out[(size_t)blockIdx.y * n + (blockIdx.x * 4 + w2) * 64 + row] = s;
    }
}

// ------------------------------------------------------------ loss
// Wave = 32 rows; WG = 128 rows. grid = (n/128, NSL_LOSS), slice = n/NSL_LOSS.
// Prologue finalizes a_l2e for WG rows and b_l2e for slice cols from psums.
__global__ __launch_bounds__(256, 4) void sink_loss(
    const unsigned short* __restrict__ Xh, const unsigned short* __restrict__ Xl,
    const unsigned short* __restrict__ Yh, const unsigned short* __restrict__ Yl,
    const float* __restrict__ apsum, const float* __restrict__ bpsum,
    const float* __restrict__ xsq, const float* __restrict__ ysq,
    float* __restrict__ partials, int n, float base_l2e) {
    __shared__ float bcl[512];
    __shared__ float ysl[512];
    __shared__ float arowl[128];
    __shared__ float xsl[128];
    __shared__ float red[256];

    const int tid = threadIdx.x;
    const int w = tid >> 6, lane = tid & 63;
    const int mrow = lane & 15, quad = lane >> 4, koff = quad * 8;
    const int i0 = (blockIdx.x * 4 + w) * 32;
    const int jbeg = blockIdx.y * (n / NSL_LOSS);   // 512 cols

    // prologue: b bias + ysq for slice cols (2 cols/thread)
#pragma unroll
    for (int h = 0; h < 2; ++h) {
        int c = tid + h * 256;
        int j = jbeg + c;
        float s = 0.f;
#pragma unroll
        for (int k = 0; k < NPS; ++k) s += bpsum[(size_t)k * n + j];
        bcl[c] = base_l2e - __log2f(s);
        ysl[c] = ysq[j];
    }
    if (tid < 128) {   // a bias + xsq for WG rows
        int i = blockIdx.x * 128 + tid;
        float s = 0.f;
#pragma unroll
        for (int k = 0; k < NPS; ++k) s += apsum[(size_t)k * n + i];
        arowl[tid] = base_l2e - __log2f(s);
        xsl[tid] = xsq[i];
    }

    short8 aH[2], aL[2];
#pragma unroll
    for (int t = 0; t < 2; ++t) {
        size_t rb = (size_t)(i0 + t * 16 + mrow) * KDIM + koff;
        aH[t] = *(const short8*)(Xh + rb);
        aL[t] = *(const short8*)(Xl + rb);
    }
    __syncthreads();

    float ar[8], xs[8];
#pragma unroll
    for (int t = 0; t < 2; ++t)
#pragma unroll
        for (int r = 0; r < 4; ++r) {
            int rl = w * 32 + t * 16 + quad * 4 + r;
            ar[t * 4 + r] = arowl[rl];
            xs[t * 4 + r] = xsl[rl];
        }

    const float c2 = 2.0f * LOG2E;
    float acc = 0.f;

    for (int jt = 0; jt < n / NSL_LOSS; jt += 32) {
        short8 bH[2], bL[2]; float bc[2], ysv[2];
#pragma unroll
        for (int u = 0; u < 2; ++u) {
            int cl = jt + u * 16 + mrow;
            size_t rb = (size_t)(jbeg + cl) * KDIM + koff;
            bH[u] = *(const short8*)(Yh + rb);
            bL[u] = *(const short8*)(Yl + rb);
            bc[u] = bcl[cl];
            ysv[u] = ysl[cl];
        }
#pragma unroll
        for (int t = 0; t < 2; ++t)
#pragma unroll
            for (int u = 0; u < 2; ++u) {
                f32x4 z = {0.f, 0.f, 0.f, 0.f};
                z = __builtin_amdgcn_mfma_f32_16x16x32_bf16(aH[t], bH[u], z, 0, 0, 0);
                z = __builtin_amdgcn_mfma_f32_16x16x32_bf16(aH[t], bL[u], z, 0, 0, 0);
                z = __builtin_amdgcn_mfma_f32_16x16x32_bf16(aL[t], bH[u], z, 0, 0, 0);
#pragma unroll
                for (int r = 0; r < 4; ++r) {
                    float dd = z[r];
                    float wgt = __builtin_amdgcn_exp2f(fmaf(dd, c2, ar[t * 4 + r] + bc[u]));
                    float cst = fmaf(dd, -2.f, xs[t * 4 + r] + ysv[u]);
                    acc = fmaf(cst, wgt, acc);
                }
            }
    }

    red[tid] = acc;
    __syncthreads();
#pragma unroll
    for (int s = 128; s > 0; s >>= 1) {
        if (tid < s) red[tid] += red[tid + s];
        __syncthreads();
    }
    if (tid == 0) partials[blockIdx.y * gridDim.x + blockIdx.x] = red[0];
}

// ------------------------------------------------------------ final reduce
__global__ void sink_reduce(const float* __restrict__ p, int nb,
                            float* __restrict__ out) {
    __shared__ float red[256];
    int tid = threadIdx.x;
    float v = 0.f;
    for (int i = tid; i < nb; i += 256) v += p[i];
    red[tid] = v;
    __syncthreads();
#pragma unroll
    for (int s = 128; s > 0; s >>= 1) {
        if (tid < s) red[tid] += red[tid + s];
        __syncthreads();
    }
    if (tid == 0) out[0] = red[0];
}

// ------------------------------------------------------------ launch
extern "C" void kernel_launch(void* const* d_in, const int* in_sizes, int n_in,
                              void* d_out, int out_size, void* d_ws, size_t ws_size,
                              hipStream_t stream) {
    const float* x = (const float*)d_in[0];
    const float* y = (const float*)d_in[1];
    const int n = in_sizes[0] / KDIM;                 // 8192
    const int nelem = n * KDIM;
    const float base_l2e = -LOG2E * logf((float)n);   // l2e * logmarg

    float* ws = (float*)d_ws;
    float* xsq   = ws;                                //  n
    float* ysq   = ws + n;                            //  n
    float* b_l2e = ws + 2 * n;                        //  n
    float* apsum = ws + 3 * n;                        //  NPS*n
    float* bpsum = ws + (3 + NPS) * n;                //  NPS*n
    float* part  = ws + (3 + 2 * NPS) * n;            //  pad n
    unsigned short* us = (unsigned short*)(ws + (4 + 2 * NPS) * n);
    unsigned short* xh = us;
    unsigned short* xl = us + nelem;
    unsigned short* yh = us + 2 * nelem;
    unsigned short* yl = us + 3 * nelem;

    dim3 pgrid(n / 256, NPS);                         // (32, 32) = 1024 WGs
    dim3 lgrid(n / 128, NSL_LOSS);                    // (64, 16) = 1024 WGs

    prep_split<<<(2 * nelem / 4 + 255) / 256, 256, 0, stream>>>(x, y, nelem, xh, xl, yh, yl);
    prep_sq<<<(2 * n + 255) / 256, 256, 0, stream>>>(x, y, n, xsq, ysq, b_l2e);

    // pass 0 (f): direct bias -ysq*l2e
    sink_pass<<<pgrid, 256, 0, stream>>>(xh, xl, yh, yl, b_l2e, nullptr, apsum, n, base_l2e);
    // pass 0 (g)
    sink_pass<<<pgrid, 256, 0, stream>>>(yh, yl, xh, xl, nullptr, apsum, bpsum, n, base_l2e);
    for (int t = 1; t < 10; ++t) {
        sink_pass<<<pgrid, 256, 0, stream>>>(xh, xl, yh, yl, nullptr, bpsum, apsum, n, base_l2e);
        sink_pass<<<pgrid, 256, 0, stream>>>(yh, yl, xh, xl, nullptr, apsum, bpsum, n, base_l2e);
    }
    sink_loss<<<lgrid, 256, 0, stream>>>(xh, xl, yh, yl, apsum, bpsum, xsq, ysq, part, n, base_l2e);
    sink_reduce<<<1, 256, 0, stream>>>(part, (n / 128) * NSL_LOSS, (float*)d_out);
}

// Round 5
// 406.023 us; speedup vs baseline: 6.6810x; 1.1032x over previous
//
#include <hip/hip_runtime.h>
#include <math.h>

// Sinkhorn loss, n=m=8192, K=32, eps=1, L=10 iterations.
// Round 5: (1) 2*log2e pre-folded into the x-split so MFMA emits
// z = l2e*2d directly; (2) multiplicative bias pb = (1/n)/sum(psum)
// (reciprocal finalize, per-cell update = exp2 + fmac only);
// (3) software-pipelined B-fragment prefetch (double register buffer).
//   pass:  psum_out[slice*n+i] = sum_{j in slice} exp2(z_ij) * pb_j
//   loss:  sum_ij fma(z,-ln2,xsq+ysq) * exp2(z) * pa_i * pb_j
// MFMA layouts (m89/m120-verified): A elem j = A[m=lane&15][k=(lane>>4)*8+j];
// C/D: col=lane&15, row=(lane>>4)*4+reg.

#define KDIM 32
#define NPS 32                    // psum slices (pass grid.y)
#define NSL_LOSS 16               // loss grid.y
#define LOG2E 1.44269504088896340736f
#define LN2 0.69314718055994530942f

typedef short short8 __attribute__((ext_vector_type(8)));
typedef float f32x4 __attribute__((ext_vector_type(4)));

__device__ __forceinline__ unsigned short f2bf(float f) {
    unsigned int u = __float_as_uint(f);
    u += 0x7FFF + ((u >> 16) & 1);
    return (unsigned short)(u >> 16);
}
__device__ __forceinline__ float bf2f(unsigned short b) {
    return __uint_as_float(((unsigned int)b) << 16);
}

// ------------------------------------------------------------ prep: hi/lo split
// x side is pre-scaled by 2*log2e; y side unscaled.
__global__ void prep_split(const float* __restrict__ x, const float* __restrict__ y,
                           int nelem,
                           unsigned short* __restrict__ xh, unsigned short* __restrict__ xl,
                           unsigned short* __restrict__ yh, unsigned short* __restrict__ yl) {
    int i4 = (blockIdx.x * 256 + threadIdx.x) * 4;
    if (i4 >= 2 * nelem) return;
    const float* src; unsigned short* dh; unsigned short* dl; int off; float sc;
    if (i4 < nelem) { src = x; dh = xh; dl = xl; off = i4; sc = 2.0f * LOG2E; }
    else            { src = y; dh = yh; dl = yl; off = i4 - nelem; sc = 1.0f; }
    float4 v = *(const float4*)(src + off);
    v.x *= sc; v.y *= sc; v.z *= sc; v.w *= sc;
    ushort4 h, l;
    h.x = f2bf(v.x); l.x = f2bf(v.x - bf2f(h.x));
    h.y = f2bf(v.y); l.y = f2bf(v.y - bf2f(h.y));
    h.z = f2bf(v.z); l.z = f2bf(v.z - bf2f(h.z));
    h.w = f2bf(v.w); l.w = f2bf(v.w - bf2f(h.w));
    *(ushort4*)(dh + off) = h;
    *(ushort4*)(dl + off) = l;
}

// ------------------------------------------------------------ prep: row sumsq
// xsq/ysq raw; pb0 = exp(-ysq) multiplicative init bias (g0 = 0).
__global__ void prep_sq(const float* __restrict__ x, const float* __restrict__ y,
                        int n, float* __restrict__ xsq, float* __restrict__ ysq,
                        float* __restrict__ pb0) {
    int i = blockIdx.x * blockDim.x + threadIdx.x;
    if (i >= 2 * n) return;
    const float* src = (i < n) ? x : y;
    int r = (i < n) ? i : i - n;
    const float4* p = (const float4*)(src + (size_t)r * KDIM);
    float s = 0.f;
#pragma unroll
    for (int q = 0; q < 8; ++q) {
        float4 v = p[q];
        s += v.x * v.x + v.y * v.y + v.z * v.z + v.w * v.w;
    }
    if (i < n) xsq[r] = s;
    else { ysq[r] = s; pb0[r] = __builtin_amdgcn_exp2f(-LOG2E * s); }
}

// ------------------------------------------------------------ pass
// Wave = 64 rows; WG = 4 waves = 256 rows. grid = (n/256, NPS); slice 256 cols.
__global__ __launch_bounds__(256, 4) void sink_pass(
    const unsigned short* __restrict__ Ah, const unsigned short* __restrict__ Alo,
    const unsigned short* __restrict__ Bh, const unsigned short* __restrict__ Blo,
    const float* __restrict__ pb_direct,     // pass 0: exp-bias, else null
    const float* __restrict__ psum_in,       // NPS-slice psums of prev pass
    float* __restrict__ psum_out, int n, float inv_n) {
    __shared__ float pbl[256];
    __shared__ float red[4][64][17];

    const int tid = threadIdx.x;
    const int w = tid >> 6, lane = tid & 63;
    const int mrow = lane & 15, quad = lane >> 4, koff = quad * 8;
    const int i0 = (blockIdx.x * 4 + w) * 64;
    const int jbeg = blockIdx.y * (n / NPS);

    {   // prologue: multiplicative bias for this slice's 256 cols
        int c = jbeg + tid;
        float b;
        if (pb_direct) {
            b = pb_direct[c];
        } else {
            float s = 0.f;
#pragma unroll
            for (int k = 0; k < NPS; ++k) s += psum_in[(size_t)k * n + c];
            b = inv_n / s;
        }
        pbl[tid] = b;
    }

    short8 aH[4], aL[4];
#pragma unroll
    for (int t = 0; t < 4; ++t) {
        size_t rb = (size_t)(i0 + t * 16 + mrow) * KDIM + koff;
        aH[t] = *(const short8*)(Ah + rb);
        aL[t] = *(const short8*)(Alo + rb);
    }
    __syncthreads();

    float rs[16];
#pragma unroll
    for (int q = 0; q < 16; ++q) rs[q] = 0.f;

    auto ldB = [&](int jt, short8* bh, short8* bl, float* pb) {
        const int j0 = jbeg + jt * 32;
#pragma unroll
        for (int u = 0; u < 2; ++u) {
            size_t rb = (size_t)(j0 + u * 16 + mrow) * KDIM + koff;
            bh[u] = *(const short8*)(Bh + rb);
            bl[u] = *(const short8*)(Blo + rb);
            pb[u] = pbl[jt * 32 + u * 16 + mrow];
        }
    };
    auto compute = [&](short8* bh, short8* bl, float* pb) {
#pragma unroll
        for (int t = 0; t < 4; ++t)
#pragma unroll
            for (int u = 0; u < 2; ++u) {
                f32x4 z = {0.f, 0.f, 0.f, 0.f};
                z = __builtin_amdgcn_mfma_f32_16x16x32_bf16(aH[t], bh[u], z, 0, 0, 0);
                z = __builtin_amdgcn_mfma_f32_16x16x32_bf16(aH[t], bl[u], z, 0, 0, 0);
                z = __builtin_amdgcn_mfma_f32_16x16x32_bf16(aL[t], bh[u], z, 0, 0, 0);
#pragma unroll
                for (int r = 0; r < 4; ++r)
                    rs[t * 4 + r] = fmaf(__builtin_amdgcn_exp2f(z[r]), pb[u], rs[t * 4 + r]);
            }
    };

    const int JT = (n / NPS) / 32;   // 8
    short8 bh0[2], bl0[2], bh1[2], bl1[2];
    float pb0v[2], pb1v[2];
    ldB(0, bh0, bl0, pb0v);
    for (int jt = 0; jt < JT; jt += 2) {
        ldB(jt + 1, bh1, bl1, pb1v);
        compute(bh0, bl0, pb0v);
        if (jt + 2 < JT) ldB(jt + 2, bh0, bl0, pb0v);
        compute(bh1, bl1, pb1v);
    }

#pragma unroll
    for (int t = 0; t < 4; ++t)
#pragma unroll
        for (int r = 0; r < 4; ++r)
            red[w][t * 16 + quad * 4 + r][mrow] = rs[t * 4 + r];
    __syncthreads();
    {
        int w2 = tid >> 6, row = tid & 63;
        float s = 0.f;
#pragma unroll
        for (int c = 0; c < 16; ++c) s += red[w2][row][c];
        psum_out[(size_t)blockIdx.y * n + (blockIdx.x * 4 + w2) * 64 + row] = s;
    }
}

// ------------------------------------------------------------ loss
// Wave = 32 rows; WG = 128 rows. grid = (n/128, NSL_LOSS), slice 512 cols.
__global__ __launch_bounds__(256, 4) void sink_loss(
    const unsigned short* __restrict__ Xh, const unsigned short* __restrict__ Xl,
    const unsigned short* __restrict__ Yh, const unsigned short* __restrict__ Yl,
    const float* __restrict__ apsum, const float* __restrict__ bpsum,
    const float* __restrict__ xsq, const float* __restrict__ ysq,
    float* __restrict__ partials, int n, float inv_n) {
    __shared__ float pbL[512];
    __shared__ float ysl[512];
    __shared__ float pal[128];
    __shared__ float xsl[128];
    __shared__ float red[256];

    const int tid = threadIdx.x;
    const int w = tid >> 6, lane = tid & 63;
    const int mrow = lane & 15, quad = lane >> 4, koff = quad * 8;
    const int i0 = (blockIdx.x * 4 + w) * 32;
    const int jbeg = blockIdx.y * (n / NSL_LOSS);   // 512 cols

#pragma unroll
    for (int h = 0; h < 2; ++h) {
        int c = tid + h * 256;
        int j = jbeg + c;
        float s = 0.f;
#pragma unroll
        for (int k = 0; k < NPS; ++k) s += bpsum[(size_t)k * n + j];
        pbL[c] = inv_n / s;
        ysl[c] = ysq[j];
    }
    if (tid < 128) {
        int i = blockIdx.x * 128 + tid;
        float s = 0.f;
#pragma unroll
        for (int k = 0; k < NPS; ++k) s += apsum[(size_t)k * n + i];
        pal[tid] = inv_n / s;
        xsl[tid] = xsq[i];
    }

    short8 aH[2], aL[2];
#pragma unroll
    for (int t = 0; t < 2; ++t) {
        size_t rb = (size_t)(i0 + t * 16 + mrow) * KDIM + koff;
        aH[t] = *(const short8*)(Xh + rb);
        aL[t] = *(const short8*)(Xl + rb);
    }
    __syncthreads();

    float pa[8], xs[8];
#pragma unroll
    for (int t = 0; t < 2; ++t)
#pragma unroll
        for (int r = 0; r < 4; ++r) {
            int rl = w * 32 + t * 16 + quad * 4 + r;
            pa[t * 4 + r] = pal[rl];
            xs[t * 4 + r] = xsl[rl];
        }

    float acc = 0.f;

    auto ldB = [&](int jt, short8* bh, short8* bl, float* pb, float* ysv) {
#pragma unroll
        for (int u = 0; u < 2; ++u) {
            int cl = jt * 32 + u * 16 + mrow;
            size_t rb = (size_t)(jbeg + cl) * KDIM + koff;
            bh[u] = *(const short8*)(Yh + rb);
            bl[u] = *(const short8*)(Yl + rb);
            pb[u] = pbL[cl];
            ysv[u] = ysl[cl];
        }
    };
    auto compute = [&](short8* bh, short8* bl, float* pb, float* ysv) {
#pragma unroll
        for (int t = 0; t < 2; ++t)
#pragma unroll
            for (int u = 0; u < 2; ++u) {
                f32x4 z = {0.f, 0.f, 0.f, 0.f};
                z = __builtin_amdgcn_mfma_f32_16x16x32_bf16(aH[t], bh[u], z, 0, 0, 0);
                z = __builtin_amdgcn_mfma_f32_16x16x32_bf16(aH[t], bl[u], z, 0, 0, 0);
                z = __builtin_amdgcn_mfma_f32_16x16x32_bf16(aL[t], bh[u], z, 0, 0, 0);
#pragma unroll
                for (int r = 0; r < 4; ++r) {
                    float dd = z[r];
                    float e = __builtin_amdgcn_exp2f(dd) * (pa[t * 4 + r] * pb[u]);
                    float cst = fmaf(dd, -LN2, xs[t * 4 + r] + ysv[u]);
                    acc = fmaf(cst, e, acc);
                }
            }
    };

    const int JT = (n / NSL_LOSS) / 32;   // 16
    short8 bh0[2], bl0[2], bh1[2], bl1[2];
    float pb0v[2], pb1v[2], ys0v[2], ys1v[2];
    ldB(0, bh0, bl0, pb0v, ys0v);
    for (int jt = 0; jt < JT; jt += 2) {
        ldB(jt + 1, bh1, bl1, pb1v, ys1v);
        compute(bh0, bl0, pb0v, ys0v);
        if (jt + 2 < JT) ldB(jt + 2, bh0, bl0, pb0v, ys0v);
        compute(bh1, bl1, pb1v, ys1v);
    }

    red[tid] = acc;
    __syncthreads();
#pragma unroll
    for (int s = 128; s > 0; s >>= 1) {
        if (tid < s) red[tid] += red[tid + s];
        __syncthreads();
    }
    if (tid == 0) partials[blockIdx.y * gridDim.x + blockIdx.x] = red[0];
}

// ------------------------------------------------------------ final reduce
__global__ void sink_reduce(const float* __restrict__ p, int nb,
                            float* __restrict__ out) {
    __shared__ float red[256];
    int tid = threadIdx.x;
    float v = 0.f;
    for (int i = tid; i < nb; i += 256) v += p[i];
    red[tid] = v;
    __syncthreads();
#pragma unroll
    for (int s = 128; s > 0; s >>= 1) {
        if (tid < s) red[tid] += red[tid + s];
        __syncthreads();
    }
    if (tid == 0) out[0] = red[0];
}

// ------------------------------------------------------------ launch
extern "C" void kernel_launch(void* const* d_in, const int* in_sizes, int n_in,
                              void* d_out, int out_size, void* d_ws, size_t ws_size,
                              hipStream_t stream) {
    const float* x = (const float*)d_in[0];
    const float* y = (const float*)d_in[1];
    const int n = in_sizes[0] / KDIM;                 // 8192
    const int nelem = n * KDIM;
    const float inv_n = 1.0f / (float)n;

    float* ws = (float*)d_ws;
    float* xsq   = ws;                                //  n
    float* ysq   = ws + n;                            //  n
    float* pb0   = ws + 2 * n;                        //  n
    float* apsum = ws + 3 * n;                        //  NPS*n
    float* bpsum = ws + (3 + NPS) * n;                //  NPS*n
    float* part  = ws + (3 + 2 * NPS) * n;            //  pad n
    unsigned short* us = (unsigned short*)(ws + (4 + 2 * NPS) * n);
    unsigned short* xh = us;
    unsigned short* xl = us + nelem;
    unsigned short* yh = us + 2 * nelem;
    unsigned short* yl = us + 3 * nelem;

    dim3 pgrid(n / 256, NPS);                         // (32, 32) = 1024 WGs
    dim3 lgrid(n / 128, NSL_LOSS);                    // (64, 16) = 1024 WGs

    prep_split<<<(2 * nelem / 4 + 255) / 256, 256, 0, stream>>>(x, y, nelem, xh, xl, yh, yl);
    prep_sq<<<(2 * n + 255) / 256, 256, 0, stream>>>(x, y, n, xsq, ysq, pb0);

    sink_pass<<<pgrid, 256, 0, stream>>>(xh, xl, yh, yl, pb0, nullptr, apsum, n, inv_n);
    sink_pass<<<pgrid, 256, 0, stream>>>(yh, yl, xh, xl, nullptr, apsum, bpsum, n, inv_n);
    for (int t = 1; t < 10; ++t) {
        sink_pass<<<pgrid, 256, 0, stream>>>(xh, xl, yh, yl, nullptr, bpsum, apsum, n, inv_n);
        sink_pass<<<pgrid, 256, 0, stream>>>(yh, yl, xh, xl, nullptr, apsum, bpsum, n, inv_n);
    }
    sink_loss<<<lgrid, 256, 0, stream>>>(xh, xl, yh, yl, apsum, bpsum, xsq, ysq, part, n, inv_n);
    sink_reduce<<<1, 256, 0, stream>>>(part, (n / 128) * NSL_LOSS, (float*)d_out);
}